// Round 16
// baseline (188.217 us; speedup 1.0000x reference)
//
#include <hip/hip_runtime.h>

#define N_NODES 100000
#define N_EDGES 3200000
#define N_QUADS (N_EDGES / 4)            // 800000

// ---- geometry ----
// DEG pass: u8 hist covers ALL nodes in 102.4KB LDS -> P=1, each edge examined
// ONCE, no predication. 256 slice-blocks, 3125 quads each.
// SCATTER pass: float hist forces P=4 (25600 nodes/partition), 64 slices,
// XCD-locality p=bid>>6 slice=bid&63 (same-slice blocks co-XCD, 64%8==0).
// Both flush by STREAMING stores to disjoint partial rows (r13: atomic flush
// was ~35us/kernel; streaming fix measured -29us total).
// r15: 4-quad ILP in hist loops (-3.5us). r16: consumers vectorized 4 nodes/
// thread (uint byte-pack / float4) -- they were load-issue-bound, not byte-bound.
#define NTOT     102400                  // padded node count (4*25600)
#define DSLICES  256
#define DSLICE_Q (N_QUADS / DSLICES)     // 3125 quads per deg slice (exact)
#define P_PARTS  4
#define PART     25600
#define SLICES   64
#define SLICE_Q  (N_QUADS / SLICES)      // 12500 quads per scatter slice
#define BLOCKS_H 256
#define T_HIST   1024

// ---------------- workspace layout (bytes) ----------------
#define OFF_STATS   0                    // double[5] (zeroed, 1KB pad)
#define OFF_DINV    1024                 // float[N]
#define OFF_GS      401024               // float[N]
#define OFF_PARTIAL 801024               // deg: u8[256][102400]; scatter: float[64][102400] (26.21MB, sequenced)
// total 27,015,424 B (< 27.2MB proven footprint)

// per-wave int64-vs-int32 detection: high words of first 64 int64 slots
__device__ __forceinline__ bool detect_is64(const void* ei) {
    const int* p = (const int*)ei;
    int lane = threadIdx.x & 63;
    int hi = p[2 * lane + 1];
    unsigned long long m = __ballot(hi != 0);
    return m == 0ull;  // wave-uniform
}

// ---- K1: single-pass u8 degree histogram -> streaming partial store + BN stats ----
__global__ __launch_bounds__(T_HIST) void stats_deg_kernel(
        const float* __restrict__ x, const void* __restrict__ ei,
        double* __restrict__ stats, unsigned char* __restrict__ partial8) {
    __shared__ unsigned int histw[NTOT / 4];   // u8 counts packed in u32; 102.4KB
    bool is64 = detect_is64(ei);
    const int tid = threadIdx.x;
    const int slice = blockIdx.x;              // 256 slices, P=1

    {   // vector zero
        uint4 z = make_uint4(0u, 0u, 0u, 0u);
        uint4* hz = (uint4*)histw;
        for (int i = tid; i < NTOT / 16; i += T_HIST) hz[i] = z;
    }
    __syncthreads();

    int q0 = slice * DSLICE_Q, q1 = q0 + DSLICE_Q;
    // unconditional packed-byte add: word = n>>2, lane-byte = n&3
#define DADD(N) atomicAdd(&histw[(unsigned)(N) >> 2], 1u << (((unsigned)(N) & 3u) * 8u));
    if (is64) {
        const longlong2* dq = (const longlong2*)((const long long*)ei + N_EDGES);
        int qb = q0;
        for (; qb + 4 * T_HIST <= q1; qb += 4 * T_HIST) {   // 4-quad ILP
            longlong2 a0 = dq[2 * (qb + tid)],              a1 = dq[2 * (qb + tid) + 1];
            longlong2 b0 = dq[2 * (qb + T_HIST + tid)],     b1 = dq[2 * (qb + T_HIST + tid) + 1];
            longlong2 c0 = dq[2 * (qb + 2 * T_HIST + tid)], c1 = dq[2 * (qb + 2 * T_HIST + tid) + 1];
            longlong2 d0 = dq[2 * (qb + 3 * T_HIST + tid)], d1 = dq[2 * (qb + 3 * T_HIST + tid) + 1];
            DADD((int)a0.x) DADD((int)a0.y) DADD((int)a1.x) DADD((int)a1.y)
            DADD((int)b0.x) DADD((int)b0.y) DADD((int)b1.x) DADD((int)b1.y)
            DADD((int)c0.x) DADD((int)c0.y) DADD((int)c1.x) DADD((int)c1.y)
            DADD((int)d0.x) DADD((int)d0.y) DADD((int)d1.x) DADD((int)d1.y)
        }
        for (int q = qb + tid; q < q1; q += T_HIST) {
            longlong2 a0 = dq[2 * q], a1 = dq[2 * q + 1];
            DADD((int)a0.x) DADD((int)a0.y) DADD((int)a1.x) DADD((int)a1.y)
        }
    } else {
        const int4* dq = (const int4*)((const int*)ei + N_EDGES);
        int qb = q0;
        for (; qb + 4 * T_HIST <= q1; qb += 4 * T_HIST) {   // 4-quad ILP
            int4 a = dq[qb + tid];
            int4 b = dq[qb + T_HIST + tid];
            int4 c = dq[qb + 2 * T_HIST + tid];
            int4 d = dq[qb + 3 * T_HIST + tid];
            DADD(a.x) DADD(a.y) DADD(a.z) DADD(a.w)
            DADD(b.x) DADD(b.y) DADD(b.z) DADD(b.w)
            DADD(c.x) DADD(c.y) DADD(c.z) DADD(c.w)
            DADD(d.x) DADD(d.y) DADD(d.z) DADD(d.w)
        }
        for (int q = qb + tid; q < q1; q += T_HIST) {
            int4 a = dq[q];
            DADD(a.x) DADD(a.y) DADD(a.z) DADD(a.w)
        }
    }
#undef DADD
    __syncthreads();
    // streaming flush: full u8 row, uint4 stores, no atomics
    {
        uint4* dst = (uint4*)(partial8 + (size_t)slice * NTOT);
        const uint4* src = (const uint4*)histw;
        for (int i = tid; i < NTOT / 16; i += T_HIST) dst[i] = src[i];
    }

    // ---- BN stats over x (blocks covering node range only; block-uniform guard) ----
    if (blockIdx.x * T_HIST < N_NODES) {
        __shared__ double sh[5][T_HIST / 64];
        int n = blockIdx.x * T_HIST + tid;
        double a0 = 0, a1 = 0, a2 = 0, a3 = 0, a4 = 0;
        if (n < N_NODES) {
            float2 v = ((const float2*)x)[n];
            double x0 = v.x, x1 = v.y;
            a0 = x0; a1 = x1; a2 = x0 * x0; a3 = x1 * x1; a4 = x0 * x1;
        }
        for (int off = 32; off; off >>= 1) {
            a0 += __shfl_down(a0, off);
            a1 += __shfl_down(a1, off);
            a2 += __shfl_down(a2, off);
            a3 += __shfl_down(a3, off);
            a4 += __shfl_down(a4, off);
        }
        int w = tid >> 6;
        if ((tid & 63) == 0) {
            sh[0][w] = a0; sh[1][w] = a1; sh[2][w] = a2; sh[3][w] = a3; sh[4][w] = a4;
        }
        __syncthreads();
        if (tid == 0) {
            double t0 = 0, t1 = 0, t2 = 0, t3 = 0, t4 = 0;
            for (int i = 0; i < T_HIST / 64; i++) {
                t0 += sh[0][i]; t1 += sh[1][i]; t2 += sh[2][i]; t3 += sh[3][i]; t4 += sh[4][i];
            }
            atomicAdd(&stats[0], t0);
            atomicAdd(&stats[1], t1);
            atomicAdd(&stats[2], t2);
            atomicAdd(&stats[3], t3);
            atomicAdd(&stats[4], t4);
        }
    }
}

// ---- K2: encoder, 4 nodes/thread: deg via uint loads + packed-u16-pair sums ----
__global__ void encoder_kernel(const float* __restrict__ x,
                               const double* __restrict__ stats,
                               const float* __restrict__ w1, const float* __restrict__ b1,
                               const float* __restrict__ gamma, const float* __restrict__ beta,
                               const float* __restrict__ prelu_a,
                               const float* __restrict__ w2, const float* __restrict__ b2,
                               const float* __restrict__ gcn_w, const float* __restrict__ wb,
                               const unsigned char* __restrict__ partial8,
                               float* __restrict__ dinv, float* __restrict__ gs) {
    __shared__ float sA[32], sB[32], sC[32], sV[32], sU[32];
    __shared__ float sGB;
    if (threadIdx.x < 32) {
        int c = threadIdx.x;
        double invN = 1.0 / (double)N_NODES;
        double m0 = stats[0] * invN, m1 = stats[1] * invN;
        double e00 = stats[2] * invN, e11 = stats[3] * invN, e01 = stats[4] * invN;
        double a = w1[2 * c], b = w1[2 * c + 1], t = b1[c];
        double meanH = a * m0 + b * m1 + t;
        double eh2 = a * a * e00 + b * b * e11 + 2.0 * a * b * e01 +
                     2.0 * t * (a * m0 + b * m1) + t * t;
        double var = eh2 - meanH * meanH;
        double inv = 1.0 / sqrt(var + 1e-5);
        float sc = (float)((double)gamma[c] * inv);
        float shift = beta[c] - (float)meanH * sc;
        sA[c] = (float)a * sc;
        sB[c] = (float)b * sc;
        sC[c] = (float)t * sc + shift;
        float vc = 0.f;
        for (int j = 0; j < 32; j++) vc += wb[j] * gcn_w[j * 32 + c];
        sV[c] = vc;
        float gb = b2[c] * vc;
        for (int off = 16; off; off >>= 1) gb += __shfl_down(gb, off, 32);
        if (c == 0) sGB = gb;
    }
    __syncthreads();
    if (threadIdx.x < 32) {
        float u = 0.f;
        for (int c = 0; c < 32; c++) u += sV[c] * w2[c * 32 + threadIdx.x];
        sU[threadIdx.x] = u;
    }
    __syncthreads();
    float alpha = prelu_a[0];
    int t = blockIdx.x * blockDim.x + threadIdx.x;   // node-quad index
    int n0 = t * 4;
    if (n0 < N_NODES) {   // N_NODES % 4 == 0 -> all 4 nodes valid
        // 256 u8 rows, 4 nodes per uint; packed-u16-pair accumulation.
        // Field max = 255*256 = 65280 < 65536 (no overflow); 2 indep chains.
        const unsigned* pd = (const unsigned*)(partial8 + n0);
        unsigned lo0 = 0, hi0 = 0, lo1 = 0, hi1 = 0;
#pragma unroll 16
        for (int s = 0; s < DSLICES; s += 2) {
            unsigned v0 = pd[(size_t)s * (NTOT / 4)];
            unsigned v1 = pd[(size_t)(s + 1) * (NTOT / 4)];
            lo0 += v0 & 0x00FF00FFu;
            hi0 += (v0 >> 8) & 0x00FF00FFu;
            lo1 += v1 & 0x00FF00FFu;
            hi1 += (v1 >> 8) & 0x00FF00FFu;
        }
        unsigned accLo = lo0 + lo1, accHi = hi0 + hi1;
        float degs[4];
        degs[0] = (float)(accLo & 0xFFFFu);   // node n0
        degs[1] = (float)(accHi & 0xFFFFu);   // node n0+1
        degs[2] = (float)(accLo >> 16);       // node n0+2
        degs[3] = (float)(accHi >> 16);       // node n0+3

        float4 x01 = ((const float4*)x)[2 * t];       // nodes n0, n0+1
        float4 x23 = ((const float4*)x)[2 * t + 1];   // nodes n0+2, n0+3
        float xa[4], xb[4];
        xa[0] = x01.x; xb[0] = x01.y;
        xa[1] = x01.z; xb[1] = x01.w;
        xa[2] = x23.x; xb[2] = x23.y;
        xa[3] = x23.z; xb[3] = x23.w;

        float dv[4], gv[4];
#pragma unroll
        for (int j = 0; j < 4; j++) {
            float g = sGB;
#pragma unroll
            for (int c = 0; c < 32; c++) {
                float hb = sA[c] * xa[j] + sB[c] * xb[j] + sC[c];
                float pc = hb >= 0.f ? hb : alpha * hb;
                g += pc * sU[c];
            }
            float di = rsqrtf(degs[j] + 1.0f);
            dv[j] = di;
            gv[j] = di * g;   // also the self-loop seed
        }
        ((float4*)dinv)[t] = make_float4(dv[0], dv[1], dv[2], dv[3]);
        ((float4*)gs)[t]   = make_float4(gv[0], gv[1], gv[2], gv[3]);
    }
}

// ---- K3: scatter histogram (P=4 float, 4-quad ILP) -> streaming partial store ----
__global__ __launch_bounds__(T_HIST) void scatter_kernel(
        const void* __restrict__ ei, const float* __restrict__ gs,
        float* __restrict__ partial) {
    __shared__ float hist[PART];
    bool is64 = detect_is64(ei);
    const int tid = threadIdx.x;
    const int p = blockIdx.x >> 6;       // XCD-locality mapping
    const int slice = blockIdx.x & 63;
    const int base = p * PART;

    {   // vector zero
        float4 z = make_float4(0.f, 0.f, 0.f, 0.f);
        float4* hz = (float4*)hist;
        for (int i = tid; i < PART / 4; i += T_HIST) hz[i] = z;
    }
    __syncthreads();

    int q0 = slice * SLICE_Q, q1 = q0 + SLICE_Q;
    if (is64) {
        const longlong2* sq = (const longlong2*)((const long long*)ei);
        const longlong2* dq = (const longlong2*)((const long long*)ei + N_EDGES);
#define SCE(sa, sb, da, db) { \
        unsigned l0 = (unsigned)((int)(da).x - base); \
        unsigned l1 = (unsigned)((int)(da).y - base); \
        unsigned l2 = (unsigned)((int)(db).x - base); \
        unsigned l3 = (unsigned)((int)(db).y - base); \
        if (l0 < PART) atomicAdd(&hist[l0], gs[(int)(sa).x]); \
        if (l1 < PART) atomicAdd(&hist[l1], gs[(int)(sa).y]); \
        if (l2 < PART) atomicAdd(&hist[l2], gs[(int)(sb).x]); \
        if (l3 < PART) atomicAdd(&hist[l3], gs[(int)(sb).y]); }
        int qb = q0;
        for (; qb + 4 * T_HIST <= q1; qb += 4 * T_HIST) {   // 4-quad ILP
            longlong2 sa0 = sq[2 * (qb + tid)],              sa1 = sq[2 * (qb + tid) + 1];
            longlong2 da0 = dq[2 * (qb + tid)],              da1 = dq[2 * (qb + tid) + 1];
            longlong2 sb0 = sq[2 * (qb + T_HIST + tid)],     sb1 = sq[2 * (qb + T_HIST + tid) + 1];
            longlong2 db0 = dq[2 * (qb + T_HIST + tid)],     db1 = dq[2 * (qb + T_HIST + tid) + 1];
            longlong2 sc0 = sq[2 * (qb + 2 * T_HIST + tid)], sc1 = sq[2 * (qb + 2 * T_HIST + tid) + 1];
            longlong2 dc0 = dq[2 * (qb + 2 * T_HIST + tid)], dc1 = dq[2 * (qb + 2 * T_HIST + tid) + 1];
            longlong2 sd0 = sq[2 * (qb + 3 * T_HIST + tid)], sd1 = sq[2 * (qb + 3 * T_HIST + tid) + 1];
            longlong2 dd0 = dq[2 * (qb + 3 * T_HIST + tid)], dd1 = dq[2 * (qb + 3 * T_HIST + tid) + 1];
            SCE(sa0, sa1, da0, da1)
            SCE(sb0, sb1, db0, db1)
            SCE(sc0, sc1, dc0, dc1)
            SCE(sd0, sd1, dd0, dd1)
        }
        for (int q = qb + tid; q < q1; q += T_HIST) {
            longlong2 sa0 = sq[2 * q], sa1 = sq[2 * q + 1];
            longlong2 da0 = dq[2 * q], da1 = dq[2 * q + 1];
            SCE(sa0, sa1, da0, da1)
        }
#undef SCE
    } else {
        const int4* sq = (const int4*)((const int*)ei);
        const int4* dq = (const int4*)((const int*)ei + N_EDGES);
#define SC4(S, D) { \
        unsigned l0 = (unsigned)((D).x - base); \
        unsigned l1 = (unsigned)((D).y - base); \
        unsigned l2 = (unsigned)((D).z - base); \
        unsigned l3 = (unsigned)((D).w - base); \
        if (l0 < PART) atomicAdd(&hist[l0], gs[(S).x]); \
        if (l1 < PART) atomicAdd(&hist[l1], gs[(S).y]); \
        if (l2 < PART) atomicAdd(&hist[l2], gs[(S).z]); \
        if (l3 < PART) atomicAdd(&hist[l3], gs[(S).w]); }
        int qb = q0;
        for (; qb + 4 * T_HIST <= q1; qb += 4 * T_HIST) {   // 4-quad ILP
            int4 sa = sq[qb + tid];
            int4 da = dq[qb + tid];
            int4 sb = sq[qb + T_HIST + tid];
            int4 db = dq[qb + T_HIST + tid];
            int4 sc = sq[qb + 2 * T_HIST + tid];
            int4 dc = dq[qb + 2 * T_HIST + tid];
            int4 sd = sq[qb + 3 * T_HIST + tid];
            int4 dd = dq[qb + 3 * T_HIST + tid];
            SC4(sa, da) SC4(sb, db) SC4(sc, dc) SC4(sd, dd)
        }
        for (int q = qb + tid; q < q1; q += T_HIST) {
            int4 sa = sq[q];
            int4 da = dq[q];
            SC4(sa, da)
        }
#undef SC4
    }
    __syncthreads();
    // streaming flush: full partition range, float4, no atomics
    {
        float4* dst = (float4*)(partial + (size_t)slice * NTOT + base);
        const float4* src = (const float4*)hist;
        for (int i = tid; i < PART / 4; i += T_HIST) dst[i] = src[i];
    }
}

// ---- K4: finalize, 4 nodes/thread via float4: out = dinv*(gs + sum_s partial) + c ----
__global__ void finalize_kernel(const float* __restrict__ dinv, const float* __restrict__ gs,
                                const float* __restrict__ partial,
                                const float* __restrict__ gcn_b, const float* __restrict__ wb,
                                const float* __restrict__ bb, float* __restrict__ out) {
    __shared__ float scc;
    if (threadIdx.x < 32) {
        float pv = wb[threadIdx.x] * gcn_b[threadIdx.x];
        for (int off = 16; off; off >>= 1) pv += __shfl_down(pv, off, 32);
        if (threadIdx.x == 0) scc = pv + bb[0];
    }
    __syncthreads();
    int t = blockIdx.x * blockDim.x + threadIdx.x;   // node-quad index
    int n0 = t * 4;
    if (n0 < N_NODES) {   // N_NODES % 4 == 0
        const float4* ps = (const float4*)(partial + n0);
        float4 a0 = make_float4(0.f, 0.f, 0.f, 0.f);
        float4 a1 = make_float4(0.f, 0.f, 0.f, 0.f);
        float4 a2 = make_float4(0.f, 0.f, 0.f, 0.f);
        float4 a3 = make_float4(0.f, 0.f, 0.f, 0.f);
#pragma unroll 4
        for (int s = 0; s < SLICES; s += 4) {
            float4 v0 = ps[(size_t)(s + 0) * (NTOT / 4)];
            float4 v1 = ps[(size_t)(s + 1) * (NTOT / 4)];
            float4 v2 = ps[(size_t)(s + 2) * (NTOT / 4)];
            float4 v3 = ps[(size_t)(s + 3) * (NTOT / 4)];
            a0.x += v0.x; a0.y += v0.y; a0.z += v0.z; a0.w += v0.w;
            a1.x += v1.x; a1.y += v1.y; a1.z += v1.z; a1.w += v1.w;
            a2.x += v2.x; a2.y += v2.y; a2.z += v2.z; a2.w += v2.w;
            a3.x += v3.x; a3.y += v3.y; a3.z += v3.z; a3.w += v3.w;
        }
        float4 g4 = ((const float4*)gs)[t];
        float4 d4 = ((const float4*)dinv)[t];
        float4 o;
        o.x = d4.x * (g4.x + (a0.x + a1.x) + (a2.x + a3.x)) + scc;
        o.y = d4.y * (g4.y + (a0.y + a1.y) + (a2.y + a3.y)) + scc;
        o.z = d4.z * (g4.z + (a0.z + a1.z) + (a2.z + a3.z)) + scc;
        o.w = d4.w * (g4.w + (a0.w + a1.w) + (a2.w + a3.w)) + scc;
        ((float4*)out)[t] = o;
    }
}

extern "C" void kernel_launch(void* const* d_in, const int* in_sizes, int n_in,
                              void* d_out, int out_size, void* d_ws, size_t ws_size,
                              hipStream_t stream) {
    const float* x       = (const float*)d_in[0];
    const void*  ei      = d_in[1];
    const float* w1      = (const float*)d_in[2];
    const float* b1      = (const float*)d_in[3];
    const float* bn_g    = (const float*)d_in[4];
    const float* bn_b    = (const float*)d_in[5];
    const float* prelu_a = (const float*)d_in[6];
    const float* w2      = (const float*)d_in[7];
    const float* b2      = (const float*)d_in[8];
    const float* gcn_w   = (const float*)d_in[9];
    const float* gcn_b   = (const float*)d_in[10];
    const float* wb      = (const float*)d_in[11];
    const float* bb      = (const float*)d_in[12];
    float* out = (float*)d_out;

    char* base = (char*)d_ws;
    double*        stats    = (double*)(base + OFF_STATS);
    float*         dinv     = (float*)(base + OFF_DINV);
    float*         gs       = (float*)(base + OFF_GS);
    unsigned char* partial8 = (unsigned char*)(base + OFF_PARTIAL);
    float*         partial  = (float*)(base + OFF_PARTIAL);   // reused after encoder reads u8

    // zero stats only (partials fully overwritten each pass)
    hipMemsetAsync(d_ws, 0, 1024, stream);

    const int NQUAD_T = (N_NODES / 4 + 255) / 256;   // 98 full + tail -> 98*256=25088 >= 25000? yes: 98 blocks cover 25088
    stats_deg_kernel<<<DSLICES, T_HIST, 0, stream>>>(x, ei, stats, partial8);
    encoder_kernel<<<NQUAD_T, 256, 0, stream>>>(
        x, stats, w1, b1, bn_g, bn_b, prelu_a, w2, b2, gcn_w, wb, partial8, dinv, gs);
    scatter_kernel<<<BLOCKS_H, T_HIST, 0, stream>>>(ei, gs, partial);
    finalize_kernel<<<NQUAD_T, 256, 0, stream>>>(
        dinv, gs, partial, gcn_b, wb, bb, out);
}

// Round 17
// 146.451 us; speedup vs baseline: 1.2852x; 1.2852x over previous
//
#include <hip/hip_runtime.h>

#define N_NODES 100000
#define N_EDGES 3200000
#define N_QUADS (N_EDGES / 4)            // 800000

// ---- geometry ----
// DEG pass: u8 hist covers ALL nodes in 102.4KB LDS -> P=1, each edge examined
// ONCE, no predication. 256 slice-blocks, 3125 quads each.
// SCATTER pass: float hist forces P=4 (25600 nodes/partition), 64 slices,
// XCD-locality p=bid>>6 slice=bid&63 (same-slice blocks co-XCD, 64%8==0).
// Both flush by STREAMING stores to disjoint partial rows (r13: atomic flush
// was ~35us/kernel; streaming -29us). r15: 4-quad ILP in hist loops (-3.5us).
// r17: consumers use 2D split -- 4 waves each sum 1/4 of slice rows for the
// block's 64 node-quads (vector loads), LDS-reduce, then 1 node/thread finish.
// (r16 lesson: 4-nodes/thread with a 98-block grid = 3% occupancy, +41us.)
#define NTOT     102400                  // padded node count (4*25600)
#define DSLICES  256
#define DSLICE_Q (N_QUADS / DSLICES)     // 3125 quads per deg slice (exact)
#define P_PARTS  4
#define PART     25600
#define SLICES   64
#define SLICE_Q  (N_QUADS / SLICES)      // 12500 quads per scatter slice
#define BLOCKS_H 256
#define T_HIST   1024

// ---------------- workspace layout (bytes) ----------------
#define OFF_STATS   0                    // double[5] (zeroed, 1KB pad)
#define OFF_DINV    1024                 // float[N]
#define OFF_GS      401024               // float[N]
#define OFF_PARTIAL 801024               // deg: u8[256][102400]; scatter: float[64][102400] (26.21MB, sequenced)
// total 27,015,424 B (< 27.2MB proven footprint)

// per-wave int64-vs-int32 detection: high words of first 64 int64 slots
__device__ __forceinline__ bool detect_is64(const void* ei) {
    const int* p = (const int*)ei;
    int lane = threadIdx.x & 63;
    int hi = p[2 * lane + 1];
    unsigned long long m = __ballot(hi != 0);
    return m == 0ull;  // wave-uniform
}

// ---- K1: single-pass u8 degree histogram -> streaming partial store + BN stats ----
__global__ __launch_bounds__(T_HIST) void stats_deg_kernel(
        const float* __restrict__ x, const void* __restrict__ ei,
        double* __restrict__ stats, unsigned char* __restrict__ partial8) {
    __shared__ unsigned int histw[NTOT / 4];   // u8 counts packed in u32; 102.4KB
    bool is64 = detect_is64(ei);
    const int tid = threadIdx.x;
    const int slice = blockIdx.x;              // 256 slices, P=1

    {   // vector zero
        uint4 z = make_uint4(0u, 0u, 0u, 0u);
        uint4* hz = (uint4*)histw;
        for (int i = tid; i < NTOT / 16; i += T_HIST) hz[i] = z;
    }
    __syncthreads();

    int q0 = slice * DSLICE_Q, q1 = q0 + DSLICE_Q;
    // unconditional packed-byte add: word = n>>2, lane-byte = n&3
#define DADD(N) atomicAdd(&histw[(unsigned)(N) >> 2], 1u << (((unsigned)(N) & 3u) * 8u));
    if (is64) {
        const longlong2* dq = (const longlong2*)((const long long*)ei + N_EDGES);
        int qb = q0;
        for (; qb + 4 * T_HIST <= q1; qb += 4 * T_HIST) {   // 4-quad ILP
            longlong2 a0 = dq[2 * (qb + tid)],              a1 = dq[2 * (qb + tid) + 1];
            longlong2 b0 = dq[2 * (qb + T_HIST + tid)],     b1 = dq[2 * (qb + T_HIST + tid) + 1];
            longlong2 c0 = dq[2 * (qb + 2 * T_HIST + tid)], c1 = dq[2 * (qb + 2 * T_HIST + tid) + 1];
            longlong2 d0 = dq[2 * (qb + 3 * T_HIST + tid)], d1 = dq[2 * (qb + 3 * T_HIST + tid) + 1];
            DADD((int)a0.x) DADD((int)a0.y) DADD((int)a1.x) DADD((int)a1.y)
            DADD((int)b0.x) DADD((int)b0.y) DADD((int)b1.x) DADD((int)b1.y)
            DADD((int)c0.x) DADD((int)c0.y) DADD((int)c1.x) DADD((int)c1.y)
            DADD((int)d0.x) DADD((int)d0.y) DADD((int)d1.x) DADD((int)d1.y)
        }
        for (int q = qb + tid; q < q1; q += T_HIST) {
            longlong2 a0 = dq[2 * q], a1 = dq[2 * q + 1];
            DADD((int)a0.x) DADD((int)a0.y) DADD((int)a1.x) DADD((int)a1.y)
        }
    } else {
        const int4* dq = (const int4*)((const int*)ei + N_EDGES);
        int qb = q0;
        for (; qb + 4 * T_HIST <= q1; qb += 4 * T_HIST) {   // 4-quad ILP
            int4 a = dq[qb + tid];
            int4 b = dq[qb + T_HIST + tid];
            int4 c = dq[qb + 2 * T_HIST + tid];
            int4 d = dq[qb + 3 * T_HIST + tid];
            DADD(a.x) DADD(a.y) DADD(a.z) DADD(a.w)
            DADD(b.x) DADD(b.y) DADD(b.z) DADD(b.w)
            DADD(c.x) DADD(c.y) DADD(c.z) DADD(c.w)
            DADD(d.x) DADD(d.y) DADD(d.z) DADD(d.w)
        }
        for (int q = qb + tid; q < q1; q += T_HIST) {
            int4 a = dq[q];
            DADD(a.x) DADD(a.y) DADD(a.z) DADD(a.w)
        }
    }
#undef DADD
    __syncthreads();
    // streaming flush: full u8 row, uint4 stores, no atomics
    {
        uint4* dst = (uint4*)(partial8 + (size_t)slice * NTOT);
        const uint4* src = (const uint4*)histw;
        for (int i = tid; i < NTOT / 16; i += T_HIST) dst[i] = src[i];
    }

    // ---- BN stats over x (blocks covering node range only; block-uniform guard) ----
    if (blockIdx.x * T_HIST < N_NODES) {
        __shared__ double sh[5][T_HIST / 64];
        int n = blockIdx.x * T_HIST + tid;
        double a0 = 0, a1 = 0, a2 = 0, a3 = 0, a4 = 0;
        if (n < N_NODES) {
            float2 v = ((const float2*)x)[n];
            double x0 = v.x, x1 = v.y;
            a0 = x0; a1 = x1; a2 = x0 * x0; a3 = x1 * x1; a4 = x0 * x1;
        }
        for (int off = 32; off; off >>= 1) {
            a0 += __shfl_down(a0, off);
            a1 += __shfl_down(a1, off);
            a2 += __shfl_down(a2, off);
            a3 += __shfl_down(a3, off);
            a4 += __shfl_down(a4, off);
        }
        int w = tid >> 6;
        if ((tid & 63) == 0) {
            sh[0][w] = a0; sh[1][w] = a1; sh[2][w] = a2; sh[3][w] = a3; sh[4][w] = a4;
        }
        __syncthreads();
        if (tid == 0) {
            double t0 = 0, t1 = 0, t2 = 0, t3 = 0, t4 = 0;
            for (int i = 0; i < T_HIST / 64; i++) {
                t0 += sh[0][i]; t1 += sh[1][i]; t2 += sh[2][i]; t3 += sh[3][i]; t4 += sh[4][i];
            }
            atomicAdd(&stats[0], t0);
            atomicAdd(&stats[1], t1);
            atomicAdd(&stats[2], t2);
            atomicAdd(&stats[3], t3);
            atomicAdd(&stats[4], t4);
        }
    }
}

// ---- K2: encoder, 2D split: 4 waves x 64 rows each -> LDS reduce -> 1 node/thread ----
__global__ __launch_bounds__(256) void encoder_kernel(
        const float* __restrict__ x,
        const double* __restrict__ stats,
        const float* __restrict__ w1, const float* __restrict__ b1,
        const float* __restrict__ gamma, const float* __restrict__ beta,
        const float* __restrict__ prelu_a,
        const float* __restrict__ w2, const float* __restrict__ b2,
        const float* __restrict__ gcn_w, const float* __restrict__ wb,
        const unsigned char* __restrict__ partial8,
        float* __restrict__ dinv, float* __restrict__ gs) {
    __shared__ float sA[32], sB[32], sC[32], sV[32], sU[32];
    __shared__ float sGB;
    __shared__ unsigned redLo[4][64], redHi[4][64];   // 2KB
    if (threadIdx.x < 32) {
        int c = threadIdx.x;
        double invN = 1.0 / (double)N_NODES;
        double m0 = stats[0] * invN, m1 = stats[1] * invN;
        double e00 = stats[2] * invN, e11 = stats[3] * invN, e01 = stats[4] * invN;
        double a = w1[2 * c], b = w1[2 * c + 1], t = b1[c];
        double meanH = a * m0 + b * m1 + t;
        double eh2 = a * a * e00 + b * b * e11 + 2.0 * a * b * e01 +
                     2.0 * t * (a * m0 + b * m1) + t * t;
        double var = eh2 - meanH * meanH;
        double inv = 1.0 / sqrt(var + 1e-5);
        float sc = (float)((double)gamma[c] * inv);
        float shift = beta[c] - (float)meanH * sc;
        sA[c] = (float)a * sc;
        sB[c] = (float)b * sc;
        sC[c] = (float)t * sc + shift;
        float vc = 0.f;
        for (int j = 0; j < 32; j++) vc += wb[j] * gcn_w[j * 32 + c];
        sV[c] = vc;
        float gb = b2[c] * vc;
        for (int off = 16; off; off >>= 1) gb += __shfl_down(gb, off, 32);
        if (c == 0) sGB = gb;
    }
    __syncthreads();
    if (threadIdx.x < 32) {
        float u = 0.f;
        for (int c = 0; c < 32; c++) u += sV[c] * w2[c * 32 + threadIdx.x];
        sU[threadIdx.x] = u;
    }

    // ---- Phase A: wave sg sums rows [sg*64, sg*64+64) for the block's 64 quads ----
    {
        int nql = threadIdx.x & 63;
        int sg  = threadIdx.x >> 6;
        int nq  = blockIdx.x * 64 + nql;          // global node-quad
        unsigned lo = 0, hi = 0;
        if (nq < N_NODES / 4) {
            const unsigned* pd = (const unsigned*)partial8 + nq;
            int s0 = sg * 64;
#pragma unroll 16
            for (int s = s0; s < s0 + 64; s += 2) {
                unsigned v0 = pd[(size_t)s * (NTOT / 4)];
                unsigned v1 = pd[(size_t)(s + 1) * (NTOT / 4)];
                lo += (v0 & 0x00FF00FFu) + (v1 & 0x00FF00FFu);
                hi += ((v0 >> 8) & 0x00FF00FFu) + ((v1 >> 8) & 0x00FF00FFu);
            }
        }
        redLo[sg][nql] = lo;
        redHi[sg][nql] = hi;
    }
    __syncthreads();

    // ---- Phase B: one node per thread ----
    float alpha = prelu_a[0];
    int n = blockIdx.x * 256 + threadIdx.x;
    if (n < N_NODES) {
        int q = threadIdx.x >> 2, j = threadIdx.x & 3;
        unsigned accLo = redLo[0][q] + redLo[1][q] + redLo[2][q] + redLo[3][q];
        unsigned accHi = redHi[0][q] + redHi[1][q] + redHi[2][q] + redHi[3][q];
        // field max 4*64*255 = 65280 < 2^16 -> no overflow
        unsigned acc = (j & 1) ? accHi : accLo;
        unsigned degu = (j & 2) ? (acc >> 16) : (acc & 0xFFFFu);
        float deg = (float)degu;

        float2 xv = ((const float2*)x)[n];
        float g = sGB;
#pragma unroll
        for (int c = 0; c < 32; c++) {
            float hb = sA[c] * xv.x + sB[c] * xv.y + sC[c];
            float pc = hb >= 0.f ? hb : alpha * hb;
            g += pc * sU[c];
        }
        float di = rsqrtf(deg + 1.0f);
        dinv[n] = di;
        gs[n] = di * g;     // also the self-loop seed (dinv*gs = dinv^2*g)
    }
}

// ---- K3: scatter histogram (P=4 float, 4-quad ILP) -> streaming partial store ----
__global__ __launch_bounds__(T_HIST) void scatter_kernel(
        const void* __restrict__ ei, const float* __restrict__ gs,
        float* __restrict__ partial) {
    __shared__ float hist[PART];
    bool is64 = detect_is64(ei);
    const int tid = threadIdx.x;
    const int p = blockIdx.x >> 6;       // XCD-locality mapping
    const int slice = blockIdx.x & 63;
    const int base = p * PART;

    {   // vector zero
        float4 z = make_float4(0.f, 0.f, 0.f, 0.f);
        float4* hz = (float4*)hist;
        for (int i = tid; i < PART / 4; i += T_HIST) hz[i] = z;
    }
    __syncthreads();

    int q0 = slice * SLICE_Q, q1 = q0 + SLICE_Q;
    if (is64) {
        const longlong2* sq = (const longlong2*)((const long long*)ei);
        const longlong2* dq = (const longlong2*)((const long long*)ei + N_EDGES);
#define SCE(sa, sb, da, db) { \
        unsigned l0 = (unsigned)((int)(da).x - base); \
        unsigned l1 = (unsigned)((int)(da).y - base); \
        unsigned l2 = (unsigned)((int)(db).x - base); \
        unsigned l3 = (unsigned)((int)(db).y - base); \
        if (l0 < PART) atomicAdd(&hist[l0], gs[(int)(sa).x]); \
        if (l1 < PART) atomicAdd(&hist[l1], gs[(int)(sa).y]); \
        if (l2 < PART) atomicAdd(&hist[l2], gs[(int)(sb).x]); \
        if (l3 < PART) atomicAdd(&hist[l3], gs[(int)(sb).y]); }
        int qb = q0;
        for (; qb + 4 * T_HIST <= q1; qb += 4 * T_HIST) {   // 4-quad ILP
            longlong2 sa0 = sq[2 * (qb + tid)],              sa1 = sq[2 * (qb + tid) + 1];
            longlong2 da0 = dq[2 * (qb + tid)],              da1 = dq[2 * (qb + tid) + 1];
            longlong2 sb0 = sq[2 * (qb + T_HIST + tid)],     sb1 = sq[2 * (qb + T_HIST + tid) + 1];
            longlong2 db0 = dq[2 * (qb + T_HIST + tid)],     db1 = dq[2 * (qb + T_HIST + tid) + 1];
            longlong2 sc0 = sq[2 * (qb + 2 * T_HIST + tid)], sc1 = sq[2 * (qb + 2 * T_HIST + tid) + 1];
            longlong2 dc0 = dq[2 * (qb + 2 * T_HIST + tid)], dc1 = dq[2 * (qb + 2 * T_HIST + tid) + 1];
            longlong2 sd0 = sq[2 * (qb + 3 * T_HIST + tid)], sd1 = sq[2 * (qb + 3 * T_HIST + tid) + 1];
            longlong2 dd0 = dq[2 * (qb + 3 * T_HIST + tid)], dd1 = dq[2 * (qb + 3 * T_HIST + tid) + 1];
            SCE(sa0, sa1, da0, da1)
            SCE(sb0, sb1, db0, db1)
            SCE(sc0, sc1, dc0, dc1)
            SCE(sd0, sd1, dd0, dd1)
        }
        for (int q = qb + tid; q < q1; q += T_HIST) {
            longlong2 sa0 = sq[2 * q], sa1 = sq[2 * q + 1];
            longlong2 da0 = dq[2 * q], da1 = dq[2 * q + 1];
            SCE(sa0, sa1, da0, da1)
        }
#undef SCE
    } else {
        const int4* sq = (const int4*)((const int*)ei);
        const int4* dq = (const int4*)((const int*)ei + N_EDGES);
#define SC4(S, D) { \
        unsigned l0 = (unsigned)((D).x - base); \
        unsigned l1 = (unsigned)((D).y - base); \
        unsigned l2 = (unsigned)((D).z - base); \
        unsigned l3 = (unsigned)((D).w - base); \
        if (l0 < PART) atomicAdd(&hist[l0], gs[(S).x]); \
        if (l1 < PART) atomicAdd(&hist[l1], gs[(S).y]); \
        if (l2 < PART) atomicAdd(&hist[l2], gs[(S).z]); \
        if (l3 < PART) atomicAdd(&hist[l3], gs[(S).w]); }
        int qb = q0;
        for (; qb + 4 * T_HIST <= q1; qb += 4 * T_HIST) {   // 4-quad ILP
            int4 sa = sq[qb + tid];
            int4 da = dq[qb + tid];
            int4 sb = sq[qb + T_HIST + tid];
            int4 db = dq[qb + T_HIST + tid];
            int4 sc = sq[qb + 2 * T_HIST + tid];
            int4 dc = dq[qb + 2 * T_HIST + tid];
            int4 sd = sq[qb + 3 * T_HIST + tid];
            int4 dd = dq[qb + 3 * T_HIST + tid];
            SC4(sa, da) SC4(sb, db) SC4(sc, dc) SC4(sd, dd)
        }
        for (int q = qb + tid; q < q1; q += T_HIST) {
            int4 sa = sq[q];
            int4 da = dq[q];
            SC4(sa, da)
        }
#undef SC4
    }
    __syncthreads();
    // streaming flush: full partition range, float4, no atomics
    {
        float4* dst = (float4*)(partial + (size_t)slice * NTOT + base);
        const float4* src = (const float4*)hist;
        for (int i = tid; i < PART / 4; i += T_HIST) dst[i] = src[i];
    }
}

// ---- K4: finalize, 2D split: 4 waves x 16 rows float4 -> LDS reduce -> 1 node/thread ----
__global__ __launch_bounds__(256) void finalize_kernel(
        const float* __restrict__ dinv, const float* __restrict__ gs,
        const float* __restrict__ partial,
        const float* __restrict__ gcn_b, const float* __restrict__ wb,
        const float* __restrict__ bb, float* __restrict__ out) {
    __shared__ float scc;
    __shared__ float4 redF[4][64];   // 4KB
    if (threadIdx.x < 32) {
        float pv = wb[threadIdx.x] * gcn_b[threadIdx.x];
        for (int off = 16; off; off >>= 1) pv += __shfl_down(pv, off, 32);
        if (threadIdx.x == 0) scc = pv + bb[0];
    }

    // ---- Phase A: wave sg sums rows [sg*16, sg*16+16) for the block's 64 quads ----
    {
        int nql = threadIdx.x & 63;
        int sg  = threadIdx.x >> 6;
        int nq  = blockIdx.x * 64 + nql;          // global node-quad
        float4 a = make_float4(0.f, 0.f, 0.f, 0.f);
        if (nq < N_NODES / 4) {
            const float4* ps = (const float4*)partial + nq;
            int s0 = sg * 16;
#pragma unroll 8
            for (int s = s0; s < s0 + 16; s += 2) {
                float4 v0 = ps[(size_t)s * (NTOT / 4)];
                float4 v1 = ps[(size_t)(s + 1) * (NTOT / 4)];
                a.x += v0.x + v1.x;
                a.y += v0.y + v1.y;
                a.z += v0.z + v1.z;
                a.w += v0.w + v1.w;
            }
        }
        redF[sg][nql] = a;
    }
    __syncthreads();

    // ---- Phase B: one node per thread ----
    int n = blockIdx.x * 256 + threadIdx.x;
    if (n < N_NODES) {
        int q = threadIdx.x >> 2, j = threadIdx.x & 3;
        // runtime-j indexing into LDS is fine (ds_read, not scratch)
        float agg = ((const float*)&redF[0][q])[j] + ((const float*)&redF[1][q])[j] +
                    ((const float*)&redF[2][q])[j] + ((const float*)&redF[3][q])[j];
        out[n] = dinv[n] * (gs[n] + agg) + scc;
    }
}

extern "C" void kernel_launch(void* const* d_in, const int* in_sizes, int n_in,
                              void* d_out, int out_size, void* d_ws, size_t ws_size,
                              hipStream_t stream) {
    const float* x       = (const float*)d_in[0];
    const void*  ei      = d_in[1];
    const float* w1      = (const float*)d_in[2];
    const float* b1      = (const float*)d_in[3];
    const float* bn_g    = (const float*)d_in[4];
    const float* bn_b    = (const float*)d_in[5];
    const float* prelu_a = (const float*)d_in[6];
    const float* w2      = (const float*)d_in[7];
    const float* b2      = (const float*)d_in[8];
    const float* gcn_w   = (const float*)d_in[9];
    const float* gcn_b   = (const float*)d_in[10];
    const float* wb      = (const float*)d_in[11];
    const float* bb      = (const float*)d_in[12];
    float* out = (float*)d_out;

    char* base = (char*)d_ws;
    double*        stats    = (double*)(base + OFF_STATS);
    float*         dinv     = (float*)(base + OFF_DINV);
    float*         gs       = (float*)(base + OFF_GS);
    unsigned char* partial8 = (unsigned char*)(base + OFF_PARTIAL);
    float*         partial  = (float*)(base + OFF_PARTIAL);   // reused after encoder reads u8

    // zero stats only (partials fully overwritten each pass)
    hipMemsetAsync(d_ws, 0, 1024, stream);

    const int NB2 = (N_NODES + 255) / 256;   // 391 blocks: full grid, 100K threads
    stats_deg_kernel<<<DSLICES, T_HIST, 0, stream>>>(x, ei, stats, partial8);
    encoder_kernel<<<NB2, 256, 0, stream>>>(
        x, stats, w1, b1, bn_g, bn_b, prelu_a, w2, b2, gcn_w, wb, partial8, dinv, gs);
    scatter_kernel<<<BLOCKS_H, T_HIST, 0, stream>>>(ei, gs, partial);
    finalize_kernel<<<NB2, 256, 0, stream>>>(
        dinv, gs, partial, gcn_b, wb, bb, out);
}